// Round 9
// baseline (173.005 us; speedup 1.0000x reference)
//
#include <hip/hip_runtime.h>
#include <hip/hip_bf16.h>

// ---------------------------------------------------------------------------
// MultiLatentAttention, R7:
//   Weight-combine: W_comb^T = wqkvT @ Wd^T  (small GEMM) so
//   qkv = x @ W_comb directly — GEMM1 + latent round-trip eliminated.
//   Flash: 8-wave blocks (512 thr), 256 q/block, grid 512 -> ALL blocks
//   co-resident (2/CU); per-wave code identical to R6 (in-register P via
//   cvt_pk + permlane swaps, triple-buffered K/V, counted vmcnt).
// ---------------------------------------------------------------------------

typedef __attribute__((ext_vector_type(8))) short bf16x8;
typedef __attribute__((ext_vector_type(4))) float floatx4;
typedef __attribute__((ext_vector_type(4))) unsigned int uintx4;

#define B_   4
#define T_   2048
#define C_   1024
#define H_   16
#define D_   64
#define L_   512
#define QKV_N 1152   // 1024 q cols + 128 kv cols

__device__ __forceinline__ float EXP2F(float x) {
    float r;
    asm("v_exp_f32 %0, %1" : "=v"(r) : "v"(x));
    return r;
}

__device__ __forceinline__ unsigned short f2bf(float f) {
    unsigned int x = __float_as_uint(f);
    unsigned int r = (x + 0x7fffu + ((x >> 16) & 1u)) >> 16;
    return (unsigned short)r;
}

// pack two fp32 -> bf16x2 (lo in low half), single instruction
__device__ __forceinline__ unsigned int cvtpk_bf(float lo, float hi) {
    unsigned int r;
    asm("v_cvt_pk_bf16_f32 %0, %1, %2" : "=v"(r) : "v"(lo), "v"(hi));
    return r;
}

// D' = {D[0:31], S[0:31]}; S' = {D[32:63], S[32:63]}
__device__ __forceinline__ void pl32(unsigned int& d, unsigned int& s) {
    asm("v_permlane32_swap_b32 %0, %1" : "+v"(d), "+v"(s));
}
// 16-lane-group interleave swap
__device__ __forceinline__ void pl16(unsigned int& d, unsigned int& s) {
    asm("v_permlane16_swap_b32 %0, %1" : "+v"(d), "+v"(s));
}

// async global->LDS, 16B per lane. LDS dest = wave-uniform base + lane*16.
__device__ __forceinline__ void gload_lds16(const unsigned short* g, char* l) {
    __builtin_amdgcn_global_load_lds(
        (const __attribute__((address_space(1))) void*)g,
        (__attribute__((address_space(3))) void*)l,
        16, 0, 0);
}

// ---------------- elementwise converts ----------------
__global__ void cvt_bf16(const float* __restrict__ X, unsigned short* __restrict__ Xb, int n4) {
    int i = blockIdx.x * 256 + threadIdx.x;
    if (i >= n4) return;
    float4 v = *(const float4*)(X + (size_t)i * 4);
    ushort4 o;
    o.x = f2bf(v.x); o.y = f2bf(v.y); o.z = f2bf(v.z); o.w = f2bf(v.w);
    *(ushort4*)(Xb + (size_t)i * 4) = o;
}

// W[K][N] fp32 -> Wt[N][K] bf16 (output-coalesced), optional scale
__global__ void wtrans(const float* __restrict__ W, unsigned short* __restrict__ Wt,
                       int K, int N, float scale) {
    int idx = blockIdx.x * 256 + threadIdx.x;
    if (idx >= K * N) return;
    int n = idx / K, k = idx - n * K;
    Wt[idx] = f2bf(W[(size_t)k * N + n] * scale);
}

// qkv[B*T][1152] bf16 -> Vt[B][64][T] bf16 (v = cols 1088..1151 transposed)
__global__ void vtrans(const unsigned short* __restrict__ qkv, unsigned short* __restrict__ Vt) {
    int idx = blockIdx.x * 256 + threadIdx.x;   // B*64*T = 524288
    int t = idx & (T_ - 1);
    int d = (idx >> 11) & 63;
    int b = idx >> 17;
    Vt[idx] = qkv[((size_t)(b * T_ + t)) * QKV_N + 1024 + 64 + d];
}

// ---------------- generic bf16 GEMM: C[M][N] = A[M][K] * Bt[N][K]^T ----------------
#define BM 128
#define BN 128
#define BK 64

template <bool F32OUT>
__global__ __launch_bounds__(256) void gemm_bt(const unsigned short* __restrict__ A,
                                               const unsigned short* __restrict__ Bt,
                                               void* __restrict__ Cout,
                                               int M, int N, int K) {
    __shared__ __align__(16) char ldsA[2][BM * BK * 2];
    __shared__ __align__(16) char ldsB[2][BN * BK * 2];
    const int tid = threadIdx.x;
    const int lane = tid & 63, wave = tid >> 6;
    const int lrow = lane & 15, lhi = lane >> 4;
    const int bm = blockIdx.y * BM, bn = blockIdx.x * BN;
    const int wm = (wave >> 1) * 64, wn = (wave & 1) * 64;

    // per-thread staging source pointers (source chunk pre-swizzled:
    // LDS slot cc holds global chunk cc^(row&7))
    const unsigned short* ap[4];
    const unsigned short* bp[4];
#pragma unroll
    for (int i = 0; i < 4; ++i) {
        int c = tid + i * 256;            // 1024 chunks of 16B per array
        int row = c >> 3;
        int sc = ((c & 7) ^ (row & 7)) * 8;
        ap[i] = A + (size_t)(bm + row) * K + sc;
        bp[i] = Bt + (size_t)(bn + row) * K + sc;
    }
    const int nk = K >> 6;
    floatx4 acc[4][4] = {};

    // prologue: stage k-step 0 into buf 0
#pragma unroll
    for (int i = 0; i < 4; ++i) {
        gload_lds16(ap[i], ldsA[0] + (i * 256 + wave * 64) * 16);
        gload_lds16(bp[i], ldsB[0] + (i * 256 + wave * 64) * 16);
        ap[i] += BK; bp[i] += BK;
    }

    for (int t = 0; t < nk; ++t) {
        const int cur = t & 1;
        if (t + 1 < nk) {
#pragma unroll
            for (int i = 0; i < 4; ++i) {
                gload_lds16(ap[i], ldsA[cur ^ 1] + (i * 256 + wave * 64) * 16);
                gload_lds16(bp[i], ldsB[cur ^ 1] + (i * 256 + wave * 64) * 16);
                ap[i] += BK; bp[i] += BK;
            }
            // counted: wait this tile's 8 loads; next tile's 8 stay in flight
            asm volatile("s_waitcnt vmcnt(8)" ::: "memory");
        } else {
            asm volatile("s_waitcnt vmcnt(0)" ::: "memory");
        }
        __builtin_amdgcn_s_barrier();
        __builtin_amdgcn_sched_barrier(0);

#pragma unroll
        for (int kk = 0; kk < 2; ++kk) {
            bf16x8 af[4], bfr[4];
#pragma unroll
            for (int m = 0; m < 4; ++m) {
                int row = wm + m * 16 + lrow;
                int colb = kk * 64 + lhi * 16;
                af[m] = *(const bf16x8*)(ldsA[cur] + row * 128 + (colb ^ ((row & 7) << 4)));
            }
#pragma unroll
            for (int n = 0; n < 4; ++n) {
                int row = wn + n * 16 + lrow;
                int colb = kk * 64 + lhi * 16;
                bfr[n] = *(const bf16x8*)(ldsB[cur] + row * 128 + (colb ^ ((row & 7) << 4)));
            }
#pragma unroll
            for (int m = 0; m < 4; ++m)
#pragma unroll
                for (int n = 0; n < 4; ++n)
                    acc[m][n] = __builtin_amdgcn_mfma_f32_16x16x32_bf16(af[m], bfr[n], acc[m][n], 0, 0, 0);
        }
        __builtin_amdgcn_sched_barrier(0);
        __builtin_amdgcn_s_barrier();   // all reads of buf[cur] done before restage
    }
#pragma unroll
    for (int m = 0; m < 4; ++m)
#pragma unroll
        for (int n = 0; n < 4; ++n)
#pragma unroll
            for (int r = 0; r < 4; ++r) {
                int row = bm + wm + m * 16 + lhi * 4 + r;
                int col = bn + wn + n * 16 + lrow;
                float v = acc[m][n][r];
                if (F32OUT)
                    ((float*)Cout)[(size_t)row * N + col] = v;
                else
                    ((unsigned short*)Cout)[(size_t)row * N + col] = f2bf(v);
            }
}

// ---------------- flash attention ----------------
// 512 blocks (8 q-tiles x 16 h x 4 b) x 512 threads (8 waves, QBLK=32/wave):
// 2 blocks/CU -> ALL blocks co-resident, no serialization tail.
// Swapped QK^T (S^T = K@Q^T); q pre-scaled by 0.125*log2e so P = exp2(S);
// l via MFMA ones-column; P in registers (cvt_pk + permlane swaps).
// K/V triple-buffered, counted vmcnt(2), 1 barrier/step.
__global__ __launch_bounds__(512, 4) void flash(const unsigned short* __restrict__ QKV, // [B*T][1152]
                                                const unsigned short* __restrict__ Vt,  // [B][64][T]
                                                unsigned short* __restrict__ Y) {       // [B*T][C]
    const int id = blockIdx.x;
    const int qt = 7 - (id >> 6);       // heavy tiles dispatch first
    const int h = (id >> 2) & 15;
    const int b = id & 3;
    const int tid = threadIdx.x;
    const int lane = tid & 63, wave = tid >> 6;
    const int lrow = lane & 15, lhi = lane >> 4;

    __shared__ __align__(16) char ldsK[3][64 * 128];  // [s][d0..63] swizzled
    __shared__ __align__(16) char ldsV[3][64 * 128];  // [d][s0..63] swizzled

    const int qbase = qt * 256 + wave * 32;
    const unsigned short* KV = QKV + 1024;    // k rows, stride QKV_N
    const int nst = qt * 4 + 4;

    // per-thread staging source pointers: 512 threads, 512 chunks of 16B/tile
    const unsigned short* kp;
    const unsigned short* vp;
    {
        int c = tid;
        int row = c >> 3;
        int sc = ((c & 7) ^ (row & 7)) * 8;
        kp = KV + ((size_t)(b * T_ + row)) * QKV_N + sc;
        vp = Vt + ((size_t)(b * 64 + row)) * T_ + sc;
    }

    // Q fragments (B-operand): lane holds Q[qbase + nf*16 + lrow][kk*32 + lhi*8 + e]
    bf16x8 qf[2][2];
#pragma unroll
    for (int nf = 0; nf < 2; ++nf)
#pragma unroll
        for (int kk = 0; kk < 2; ++kk) {
            int trow = b * T_ + qbase + nf * 16 + lrow;
            int col = h * 64 + kk * 32 + lhi * 8;
            qf[nf][kk] = *(const bf16x8*)(QKV + (size_t)trow * QKV_N + col);
        }

    floatx4 o[2][4] = {};
    floatx4 ol[2] = {};   // row-sum accumulator (ones-column)

    const short one_bf = (short)0x3F80;
    const bf16x8 ones8 = {one_bf, one_bf, one_bf, one_bf, one_bf, one_bf, one_bf, one_bf};

    // prologue: stage tile 0 into buf 0
    char* kcur = ldsK[0];  char* kstg = ldsK[1];  char* kfre = ldsK[2];
    char* vcur = ldsV[0];  char* vstg = ldsV[1];  char* vfre = ldsV[2];
    gload_lds16(kp, kcur + wave * 1024);
    gload_lds16(vp, vcur + wave * 1024);
    kp += 64 * QKV_N;
    vp += 64;

    for (int st = 0; st < nst; ++st) {
        // stage tile st+1 into stg (refetch last tile on final step to keep
        // the vmcnt count uniform)
        const bool more = (st + 1 < nst);
        const long kadj = more ? 0 : -(long)(64 * QKV_N);
        const long vadj = more ? 0 : -64L;
        gload_lds16(kp + kadj, kstg + wave * 1024);
        gload_lds16(vp + vadj, vstg + wave * 1024);
        if (more) { kp += 64 * QKV_N; vp += 64; }
        // counted wait: this step's 2 loads (issued last iter) are the oldest
        asm volatile("s_waitcnt vmcnt(2)" ::: "memory");
        __builtin_amdgcn_s_barrier();
        __builtin_amdgcn_sched_barrier(0);

        if (st * 64 <= qbase + 31) {
            // S^T frags: row = s-local = mf*16+lhi*4+r, col = q-local = nf*16+lrow
            floatx4 s[4][2] = {};
#pragma unroll
            for (int kk = 0; kk < 2; ++kk) {
                bf16x8 kf[4];
#pragma unroll
                for (int mf = 0; mf < 4; ++mf) {
                    int row = mf * 16 + lrow;
                    int colb = kk * 64 + lhi * 16;
                    kf[mf] = *(const bf16x8*)(kcur + row * 128 + (colb ^ ((row & 7) << 4)));
                }
                __builtin_amdgcn_s_setprio(1);
#pragma unroll
                for (int mf = 0; mf < 4; ++mf)
#pragma unroll
                    for (int nf = 0; nf < 2; ++nf)
                        s[mf][nf] = __builtin_amdgcn_mfma_f32_16x16x32_bf16(kf[mf], qf[nf][kk], s[mf][nf], 0, 0, 0);
                __builtin_amdgcn_s_setprio(0);
            }

            // causal mask + P = exp2(S) (scale pre-folded into q)
#pragma unroll
            for (int nf = 0; nf < 2; ++nf) {
                if (st * 64 + 63 > qbase + nf * 16) {   // mask only near diagonal
                    int qg = qbase + nf * 16 + lrow;
#pragma unroll
                    for (int mf = 0; mf < 4; ++mf)
#pragma unroll
                        for (int r = 0; r < 4; ++r) {
                            int sg = st * 64 + mf * 16 + lhi * 4 + r;
                            if (sg > qg) s[mf][nf][r] = -1e30f;
                        }
                }
#pragma unroll
                for (int mf = 0; mf < 4; ++mf)
#pragma unroll
                    for (int rr = 0; rr < 4; ++rr)
                        s[mf][nf][rr] = EXP2F(s[mf][nf][rr]);
            }

            // in-register P^T -> PV A-fragment transform (cvt_pk + permlane)
            bf16x8 pfr[2][2];
#pragma unroll
            for (int nf = 0; nf < 2; ++nf)
#pragma unroll
                for (int ss = 0; ss < 2; ++ss) {
                    unsigned int A0 = cvtpk_bf(s[2 * ss][nf][0], s[2 * ss][nf][1]);
                    unsigned int A1 = cvtpk_bf(s[2 * ss][nf][2], s[2 * ss][nf][3]);
                    unsigned int B0 = cvtpk_bf(s[2 * ss + 1][nf][0], s[2 * ss + 1][nf][1]);
                    unsigned int B1 = cvtpk_bf(s[2 * ss + 1][nf][2], s[2 * ss + 1][nf][3]);
                    pl32(A0, B0); pl16(A0, B0);   // A0=word0, B0=word2
                    pl32(A1, B1); pl16(A1, B1);   // A1=word1, B1=word3
                    uintx4 pw; pw.x = A0; pw.y = A1; pw.z = B0; pw.w = B1;
                    pfr[nf][ss] = __builtin_bit_cast(bf16x8, pw);
                }

            // PV: O[q][d] += P[q][s] * V[s][d]; l[q] += P[q][s] * 1
#pragma unroll
            for (int ss = 0; ss < 2; ++ss) {
                bf16x8 vf[4];
#pragma unroll
                for (int dn = 0; dn < 4; ++dn) {
                    int row = dn * 16 + lrow;
                    int colb = ss * 64 + lhi * 16;
                    vf[dn] = *(const bf16x8*)(vcur + row * 128 + (colb ^ ((row & 7) << 4)));
                }
                __builtin_amdgcn_s_setprio(1);
#pragma unroll
                for (int m = 0; m < 2; ++m) {
#pragma unroll
                    for (int dn = 0; dn < 4; ++dn)
                        o[m][dn] = __builtin_amdgcn_mfma_f32_16x16x32_bf16(pfr[m][ss], vf[dn], o[m][dn], 0, 0, 0);
                    ol[m] = __builtin_amdgcn_mfma_f32_16x16x32_bf16(pfr[m][ss], ones8, ol[m], 0, 0, 0);
                }
                __builtin_amdgcn_s_setprio(0);
            }
        }

        // rotate buffers: cur <- stg <- fre <- cur
        char* t;
        t = kcur; kcur = kstg; kstg = kfre; kfre = t;
        t = vcur; vcur = vstg; vstg = vfre; vfre = t;
    }

    // epilogue: divide by l (ol[m][rr] is l for row m*16+lhi*4+rr), store y
#pragma unroll
    for (int m = 0; m < 2; ++m) {
        float linv[4];
#pragma unroll
        for (int rr = 0; rr < 4; ++rr) linv[rr] = __builtin_amdgcn_rcpf(ol[m][rr]);
#pragma unroll
        for (int dn = 0; dn < 4; ++dn)
#pragma unroll
            for (int rr = 0; rr < 4; ++rr) {
                int trow = b * T_ + qbase + m * 16 + lhi * 4 + rr;
                int col = h * 64 + dn * 16 + lrow;
                Y[(size_t)trow * C_ + col] = f2bf(o[m][dn][rr] * linv[rr]);
            }
    }
}

// ---------------------------------------------------------------------------
extern "C" void kernel_launch(void* const* d_in, const int* in_sizes, int n_in,
                              void* d_out, int out_size, void* d_ws, size_t ws_size,
                              hipStream_t stream) {
    (void)in_sizes; (void)n_in; (void)out_size; (void)ws_size;
    const float* x   = (const float*)d_in[0];
    const float* Wd  = (const float*)d_in[1];
    const float* Wq  = (const float*)d_in[2];
    const float* Wkv = (const float*)d_in[3];
    const float* Wp  = (const float*)d_in[4];
    float* out = (float*)d_out;
    char* ws = (char*)d_ws;

    const int BT = B_ * T_;  // 8192
    const float KSC = 0.125f * 1.44269504f;   // attn scale * log2(e), folded into Wq

    unsigned short* xb     = (unsigned short*)(ws + 0);           // 16 MB (reused as y)
    unsigned short* wqkvT  = (unsigned short*)(ws + 16777216);    // 1.125 MB [1152][512]
    unsigned short* wdb    = (unsigned short*)(ws + 17956864);    // 1 MB    [1024][512] (= Wd bf16, no transpose)
    unsigned short* wpT    = (unsigned short*)(ws + 19005440);    // 2 MB    [1024][1024]
    unsigned short* wcombT = (unsigned short*)(ws + 21102592);    // 2.25 MB [1152][1024]
    unsigned short* qkv    = (unsigned short*)(ws + 29491200);    // 18 MB   [8192][1152]
    unsigned short* vt     = (unsigned short*)(ws + 48365568);    // 1 MB    [4][64][2048]
    unsigned short* yb     = xb;                                  // alias (x consumed by qkv GEMM)

    cvt_bf16<<<(BT * C_ / 4 + 255) / 256, 256, 0, stream>>>(x, xb, BT * C_ / 4);
    cvt_bf16<<<(C_ * L_ / 4 + 255) / 256, 256, 0, stream>>>(Wd, wdb, C_ * L_ / 4);
    wtrans<<<(L_ * C_ + 255) / 256, 256, 0, stream>>>(Wq, wqkvT, L_, C_, KSC);
    wtrans<<<(L_ * 128 + 255) / 256, 256, 0, stream>>>(Wkv, wqkvT + 1024 * 512, L_, 128, 1.0f);
    wtrans<<<(C_ * C_ + 255) / 256, 256, 0, stream>>>(Wp, wpT, C_, C_, 1.0f);

    // W_comb^T[1152][1024] = wqkvT[1152][512] @ (Wd[1024][512])^T
    gemm_bt<false><<<dim3(C_ / BN, QKV_N / BM), 256, 0, stream>>>(wqkvT, wdb, wcombT, QKV_N, C_, L_);

    // qkv[8192][1152] = xb[8192][1024] @ W_comb (Bt = wcombT)
    gemm_bt<false><<<dim3(QKV_N / BN, BT / BM), 256, 0, stream>>>(xb, wcombT, qkv, BT, QKV_N, C_);

    vtrans<<<(B_ * 64 * T_ + 255) / 256, 256, 0, stream>>>(qkv, vt);

    flash<<<512, 512, 0, stream>>>(qkv, vt, yb);

    gemm_bt<true><<<dim3(C_ / BN, BT / BM), 256, 0, stream>>>(yb, wpT, out, BT, C_, C_);
}

// Round 10
// 143.898 us; speedup vs baseline: 1.2023x; 1.2023x over previous
//
#include <hip/hip_runtime.h>
#include <hip/hip_bf16.h>

// ---------------------------------------------------------------------------
// MultiLatentAttention, R8:
//   Flash reverted to R6 config (4 waves, QBLK=32/wave, grid 1024, 3 blk/CU,
//   in-register P via cvt_pk + permlane swaps, triple-buffer K/V, counted
//   vmcnt). Weight-combine kept (qkv = x @ (Wd@[Wq|Wkv])).
//   GEMMs: 1D grid + bijective XCD swizzle (T1) for L2 panel reuse.
// ---------------------------------------------------------------------------

typedef __attribute__((ext_vector_type(8))) short bf16x8;
typedef __attribute__((ext_vector_type(4))) float floatx4;
typedef __attribute__((ext_vector_type(4))) unsigned int uintx4;

#define B_   4
#define T_   2048
#define C_   1024
#define H_   16
#define D_   64
#define L_   512
#define QKV_N 1152   // 1024 q cols + 128 kv cols

__device__ __forceinline__ float EXP2F(float x) {
    float r;
    asm("v_exp_f32 %0, %1" : "=v"(r) : "v"(x));
    return r;
}

__device__ __forceinline__ unsigned short f2bf(float f) {
    unsigned int x = __float_as_uint(f);
    unsigned int r = (x + 0x7fffu + ((x >> 16) & 1u)) >> 16;
    return (unsigned short)r;
}

// pack two fp32 -> bf16x2 (lo in low half), single instruction
__device__ __forceinline__ unsigned int cvtpk_bf(float lo, float hi) {
    unsigned int r;
    asm("v_cvt_pk_bf16_f32 %0, %1, %2" : "=v"(r) : "v"(lo), "v"(hi));
    return r;
}

// D' = {D[0:31], S[0:31]}; S' = {D[32:63], S[32:63]}
__device__ __forceinline__ void pl32(unsigned int& d, unsigned int& s) {
    asm("v_permlane32_swap_b32 %0, %1" : "+v"(d), "+v"(s));
}
// 16-lane-group interleave swap
__device__ __forceinline__ void pl16(unsigned int& d, unsigned int& s) {
    asm("v_permlane16_swap_b32 %0, %1" : "+v"(d), "+v"(s));
}

// async global->LDS, 16B per lane. LDS dest = wave-uniform base + lane*16.
__device__ __forceinline__ void gload_lds16(const unsigned short* g, char* l) {
    __builtin_amdgcn_global_load_lds(
        (const __attribute__((address_space(1))) void*)g,
        (__attribute__((address_space(3))) void*)l,
        16, 0, 0);
}

// ---------------- elementwise converts ----------------
__global__ void cvt_bf16(const float* __restrict__ X, unsigned short* __restrict__ Xb, int n4) {
    int i = blockIdx.x * 256 + threadIdx.x;
    if (i >= n4) return;
    float4 v = *(const float4*)(X + (size_t)i * 4);
    ushort4 o;
    o.x = f2bf(v.x); o.y = f2bf(v.y); o.z = f2bf(v.z); o.w = f2bf(v.w);
    *(ushort4*)(Xb + (size_t)i * 4) = o;
}

// W[K][N] fp32 -> Wt[N][K] bf16 (output-coalesced), optional scale
__global__ void wtrans(const float* __restrict__ W, unsigned short* __restrict__ Wt,
                       int K, int N, float scale) {
    int idx = blockIdx.x * 256 + threadIdx.x;
    if (idx >= K * N) return;
    int n = idx / K, k = idx - n * K;
    Wt[idx] = f2bf(W[(size_t)k * N + n] * scale);
}

// qkv[B*T][1152] bf16 -> Vt[B][64][T] bf16 (v = cols 1088..1151 transposed)
__global__ void vtrans(const unsigned short* __restrict__ qkv, unsigned short* __restrict__ Vt) {
    int idx = blockIdx.x * 256 + threadIdx.x;   // B*64*T = 524288
    int t = idx & (T_ - 1);
    int d = (idx >> 11) & 63;
    int b = idx >> 17;
    Vt[idx] = qkv[((size_t)(b * T_ + t)) * QKV_N + 1024 + 64 + d];
}

// ---------------- generic bf16 GEMM: C[M][N] = A[M][K] * Bt[N][K]^T ----------------
// 1D grid (nbx*nby blocks, nwg % 8 == 0) with bijective XCD swizzle.
#define BM 128
#define BN 128
#define BK 64

template <bool F32OUT>
__global__ __launch_bounds__(256) void gemm_bt(const unsigned short* __restrict__ A,
                                               const unsigned short* __restrict__ Bt,
                                               void* __restrict__ Cout,
                                               int M, int N, int K, int nbx) {
    __shared__ __align__(16) char ldsA[2][BM * BK * 2];
    __shared__ __align__(16) char ldsB[2][BN * BK * 2];
    const int tid = threadIdx.x;
    const int lane = tid & 63, wave = tid >> 6;
    const int lrow = lane & 15, lhi = lane >> 4;

    // XCD-aware bijective remap: xcd = bid%8 gets contiguous chunk of tiles
    const int bid = blockIdx.x;
    const int cpx = gridDim.x >> 3;           // nwg/8 (nwg % 8 == 0)
    const int swz = (bid & 7) * cpx + (bid >> 3);
    const int by = swz / nbx, bx = swz - by * nbx;
    const int bm = by * BM, bn = bx * BN;
    const int wm = (wave >> 1) * 64, wn = (wave & 1) * 64;

    // per-thread staging source pointers (source chunk pre-swizzled:
    // LDS slot cc holds global chunk cc^(row&7))
    const unsigned short* ap[4];
    const unsigned short* bp[4];
#pragma unroll
    for (int i = 0; i < 4; ++i) {
        int c = tid + i * 256;            // 1024 chunks of 16B per array
        int row = c >> 3;
        int sc = ((c & 7) ^ (row & 7)) * 8;
        ap[i] = A + (size_t)(bm + row) * K + sc;
        bp[i] = Bt + (size_t)(bn + row) * K + sc;
    }
    const int nk = K >> 6;
    floatx4 acc[4][4] = {};

    // prologue: stage k-step 0 into buf 0
#pragma unroll
    for (int i = 0; i < 4; ++i) {
        gload_lds16(ap[i], ldsA[0] + (i * 256 + wave * 64) * 16);
        gload_lds16(bp[i], ldsB[0] + (i * 256 + wave * 64) * 16);
        ap[i] += BK; bp[i] += BK;
    }

    for (int t = 0; t < nk; ++t) {
        const int cur = t & 1;
        if (t + 1 < nk) {
#pragma unroll
            for (int i = 0; i < 4; ++i) {
                gload_lds16(ap[i], ldsA[cur ^ 1] + (i * 256 + wave * 64) * 16);
                gload_lds16(bp[i], ldsB[cur ^ 1] + (i * 256 + wave * 64) * 16);
                ap[i] += BK; bp[i] += BK;
            }
            // counted: wait this tile's 8 loads; next tile's 8 stay in flight
            asm volatile("s_waitcnt vmcnt(8)" ::: "memory");
        } else {
            asm volatile("s_waitcnt vmcnt(0)" ::: "memory");
        }
        __builtin_amdgcn_s_barrier();
        __builtin_amdgcn_sched_barrier(0);

#pragma unroll
        for (int kk = 0; kk < 2; ++kk) {
            bf16x8 af[4], bfr[4];
#pragma unroll
            for (int m = 0; m < 4; ++m) {
                int row = wm + m * 16 + lrow;
                int colb = kk * 64 + lhi * 16;
                af[m] = *(const bf16x8*)(ldsA[cur] + row * 128 + (colb ^ ((row & 7) << 4)));
            }
#pragma unroll
            for (int n = 0; n < 4; ++n) {
                int row = wn + n * 16 + lrow;
                int colb = kk * 64 + lhi * 16;
                bfr[n] = *(const bf16x8*)(ldsB[cur] + row * 128 + (colb ^ ((row & 7) << 4)));
            }
#pragma unroll
            for (int m = 0; m < 4; ++m)
#pragma unroll
                for (int n = 0; n < 4; ++n)
                    acc[m][n] = __builtin_amdgcn_mfma_f32_16x16x32_bf16(af[m], bfr[n], acc[m][n], 0, 0, 0);
        }
        __builtin_amdgcn_sched_barrier(0);
        __builtin_amdgcn_s_barrier();   // all reads of buf[cur] done before restage
    }
#pragma unroll
    for (int m = 0; m < 4; ++m)
#pragma unroll
        for (int n = 0; n < 4; ++n)
#pragma unroll
            for (int r = 0; r < 4; ++r) {
                int row = bm + wm + m * 16 + lhi * 4 + r;
                int col = bn + wn + n * 16 + lrow;
                float v = acc[m][n][r];
                if (F32OUT)
                    ((float*)Cout)[(size_t)row * N + col] = v;
                else
                    ((unsigned short*)Cout)[(size_t)row * N + col] = f2bf(v);
            }
}

// ---------------- flash attention (R6 config) ----------------
// 1024 blocks (16 q-tiles x 16 h x 4 b, heavy qt first), 256 threads;
// wave owns 32 q rows. Swapped QK^T (S^T = K@Q^T); q pre-scaled by
// 0.125*log2e so P = exp2(S); l via MFMA ones-column.
// P stays in registers (cvt_pk + permlane swaps). K/V triple-buffered,
// counted vmcnt(4), 1 barrier/step.
__global__ __launch_bounds__(256, 3) void flash(const unsigned short* __restrict__ QKV, // [B*T][1152]
                                                const unsigned short* __restrict__ Vt,  // [B][64][T]
                                                unsigned short* __restrict__ Y) {       // [B*T][C]
    const int id = blockIdx.x;
    const int qt = 15 - (id >> 6);      // heavy tiles dispatch first
    const int h = (id >> 2) & 15;
    const int b = id & 3;
    const int tid = threadIdx.x;
    const int lane = tid & 63, wave = tid >> 6;
    const int lrow = lane & 15, lhi = lane >> 4;

    __shared__ __align__(16) char ldsK[3][64 * 128];  // [s][d0..63] swizzled
    __shared__ __align__(16) char ldsV[3][64 * 128];  // [d][s0..63] swizzled

    const int qbase = qt * 128 + wave * 32;
    const unsigned short* KV = QKV + 1024;    // k rows, stride QKV_N
    const int nst = qt * 2 + 2;

    // per-thread staging source pointers (tile to stage next)
    const unsigned short* kp[2];
    const unsigned short* vp[2];
#pragma unroll
    for (int i = 0; i < 2; ++i) {
        int c = tid + i * 256;
        int row = c >> 3;
        int sc = ((c & 7) ^ (row & 7)) * 8;
        kp[i] = KV + ((size_t)(b * T_ + row)) * QKV_N + sc;
        vp[i] = Vt + ((size_t)(b * 64 + row)) * T_ + sc;
    }

    // Q fragments (B-operand): lane holds Q[qbase + nf*16 + lrow][kk*32 + lhi*8 + e]
    bf16x8 qf[2][2];
#pragma unroll
    for (int nf = 0; nf < 2; ++nf)
#pragma unroll
        for (int kk = 0; kk < 2; ++kk) {
            int trow = b * T_ + qbase + nf * 16 + lrow;
            int col = h * 64 + kk * 32 + lhi * 8;
            qf[nf][kk] = *(const bf16x8*)(QKV + (size_t)trow * QKV_N + col);
        }

    floatx4 o[2][4] = {};
    floatx4 ol[2] = {};   // row-sum accumulator (ones-column)

    const short one_bf = (short)0x3F80;
    const bf16x8 ones8 = {one_bf, one_bf, one_bf, one_bf, one_bf, one_bf, one_bf, one_bf};

    // prologue: stage tile 0 into buf 0
    char* kcur = ldsK[0];  char* kstg = ldsK[1];  char* kfre = ldsK[2];
    char* vcur = ldsV[0];  char* vstg = ldsV[1];  char* vfre = ldsV[2];
#pragma unroll
    for (int i = 0; i < 2; ++i) {
        gload_lds16(kp[i], kcur + (i * 256 + wave * 64) * 16);
        gload_lds16(vp[i], vcur + (i * 256 + wave * 64) * 16);
        kp[i] += 64 * QKV_N;
        vp[i] += 64;
    }

    for (int st = 0; st < nst; ++st) {
        // stage tile st+1 into stg (refetch last tile on final step to keep
        // the vmcnt count uniform)
        const bool more = (st + 1 < nst);
        const long kadj = more ? 0 : -(long)(64 * QKV_N);
        const long vadj = more ? 0 : -64L;
#pragma unroll
        for (int i = 0; i < 2; ++i) {
            gload_lds16(kp[i] + kadj, kstg + (i * 256 + wave * 64) * 16);
            gload_lds16(vp[i] + vadj, vstg + (i * 256 + wave * 64) * 16);
        }
        if (more) {
            kp[0] += 64 * QKV_N; kp[1] += 64 * QKV_N;
            vp[0] += 64;         vp[1] += 64;
        }
        // counted wait: this step's 4 loads (issued last iter) are the oldest
        asm volatile("s_waitcnt vmcnt(4)" ::: "memory");
        __builtin_amdgcn_s_barrier();
        __builtin_amdgcn_sched_barrier(0);

        if (st * 64 <= qbase + 31) {
            // S^T frags: row = s-local = mf*16+lhi*4+r, col = q-local = nf*16+lrow
            floatx4 s[4][2] = {};
#pragma unroll
            for (int kk = 0; kk < 2; ++kk) {
                bf16x8 kf[4];
#pragma unroll
                for (int mf = 0; mf < 4; ++mf) {
                    int row = mf * 16 + lrow;
                    int colb = kk * 64 + lhi * 16;
                    kf[mf] = *(const bf16x8*)(kcur + row * 128 + (colb ^ ((row & 7) << 4)));
                }
                __builtin_amdgcn_s_setprio(1);
#pragma unroll
                for (int mf = 0; mf < 4; ++mf)
#pragma unroll
                    for (int nf = 0; nf < 2; ++nf)
                        s[mf][nf] = __builtin_amdgcn_mfma_f32_16x16x32_bf16(kf[mf], qf[nf][kk], s[mf][nf], 0, 0, 0);
                __builtin_amdgcn_s_setprio(0);
            }

            // causal mask + P = exp2(S) (scale pre-folded into q)
#pragma unroll
            for (int nf = 0; nf < 2; ++nf) {
                if (st * 64 + 63 > qbase + nf * 16) {   // mask only near diagonal
                    int qg = qbase + nf * 16 + lrow;
#pragma unroll
                    for (int mf = 0; mf < 4; ++mf)
#pragma unroll
                        for (int r = 0; r < 4; ++r) {
                            int sg = st * 64 + mf * 16 + lhi * 4 + r;
                            if (sg > qg) s[mf][nf][r] = -1e30f;
                        }
                }
#pragma unroll
                for (int mf = 0; mf < 4; ++mf)
#pragma unroll
                    for (int rr = 0; rr < 4; ++rr)
                        s[mf][nf][rr] = EXP2F(s[mf][nf][rr]);
            }

            // in-register P^T -> PV A-fragment transform (cvt_pk + permlane)
            bf16x8 pfr[2][2];
#pragma unroll
            for (int nf = 0; nf < 2; ++nf)
#pragma unroll
                for (int ss = 0; ss < 2; ++ss) {
                    unsigned int A0 = cvtpk_bf(s[2 * ss][nf][0], s[2 * ss][nf][1]);
                    unsigned int A1 = cvtpk_bf(s[2 * ss][nf][2], s[2 * ss][nf][3]);
                    unsigned int B0 = cvtpk_bf(s[2 * ss + 1][nf][0], s[2 * ss + 1][nf][1]);
                    unsigned int B1 = cvtpk_bf(s[2 * ss + 1][nf][2], s[2 * ss + 1][nf][3]);
                    pl32(A0, B0); pl16(A0, B0);   // A0=word0, B0=word2
                    pl32(A1, B1); pl16(A1, B1);   // A1=word1, B1=word3
                    uintx4 pw; pw.x = A0; pw.y = A1; pw.z = B0; pw.w = B1;
                    pfr[nf][ss] = __builtin_bit_cast(bf16x8, pw);
                }

            // PV: O[q][d] += P[q][s] * V[s][d]; l[q] += P[q][s] * 1
#pragma unroll
            for (int ss = 0; ss < 2; ++ss) {
                bf16x8 vf[4];
#pragma unroll
                for (int dn = 0; dn < 4; ++dn) {
                    int row = dn * 16 + lrow;
                    int colb = ss * 64 + lhi * 16;
                    vf[dn] = *(const bf16x8*)(vcur + row * 128 + (colb ^ ((row & 7) << 4)));
                }
                __builtin_amdgcn_s_setprio(1);
#pragma unroll
                for (int m = 0; m < 2; ++m) {
#pragma unroll
                    for (int dn = 0; dn < 4; ++dn)
                        o[m][dn] = __builtin_amdgcn_mfma_f32_16x16x32_bf16(pfr[m][ss], vf[dn], o[m][dn], 0, 0, 0);
                    ol[m] = __builtin_amdgcn_mfma_f32_16x16x32_bf16(pfr[m][ss], ones8, ol[m], 0, 0, 0);
                }
                __builtin_amdgcn_s_setprio(0);
            }
        }

        // rotate buffers: cur <- stg <- fre <- cur
        char* t;
        t = kcur; kcur = kstg; kstg = kfre; kfre = t;
        t = vcur; vcur = vstg; vstg = vfre; vfre = t;
    }

    // epilogue: divide by l (ol[m][rr] is l for row m*16+lhi*4+rr), store y
#pragma unroll
    for (int m = 0; m < 2; ++m) {
        float linv[4];
#pragma unroll
        for (int rr = 0; rr < 4; ++rr) linv[rr] = __builtin_amdgcn_rcpf(ol[m][rr]);
#pragma unroll
        for (int dn = 0; dn < 4; ++dn)
#pragma unroll
            for (int rr = 0; rr < 4; ++rr) {
                int trow = b * T_ + qbase + m * 16 + lhi * 4 + rr;
                int col = h * 64 + dn * 16 + lrow;
                Y[(size_t)trow * C_ + col] = f2bf(o[m][dn][rr] * linv[rr]);
            }
    }
}

// ---------------------------------------------------------------------------
extern "C" void kernel_launch(void* const* d_in, const int* in_sizes, int n_in,
                              void* d_out, int out_size, void* d_ws, size_t ws_size,
                              hipStream_t stream) {
    (void)in_sizes; (void)n_in; (void)out_size; (void)ws_size;
    const float* x   = (const float*)d_in[0];
    const float* Wd  = (const float*)d_in[1];
    const float* Wq  = (const float*)d_in[2];
    const float* Wkv = (const float*)d_in[3];
    const float* Wp  = (const float*)d_in[4];
    float* out = (float*)d_out;
    char* ws = (char*)d_ws;

    const int BT = B_ * T_;  // 8192
    const float KSC = 0.125f * 1.44269504f;   // attn scale * log2(e), folded into Wq

    unsigned short* xb     = (unsigned short*)(ws + 0);           // 16 MB (reused as y)
    unsigned short* wqkvT  = (unsigned short*)(ws + 16777216);    // 1.125 MB [1152][512]
    unsigned short* wdb    = (unsigned short*)(ws + 17956864);    // 1 MB    [1024][512] (= Wd bf16, no transpose)
    unsigned short* wpT    = (unsigned short*)(ws + 19005440);    // 2 MB    [1024][1024]
    unsigned short* wcombT = (unsigned short*)(ws + 21102592);    // 2.25 MB [1152][1024]
    unsigned short* qkv    = (unsigned short*)(ws + 29491200);    // 18 MB   [8192][1152]
    unsigned short* vt     = (unsigned short*)(ws + 48365568);    // 1 MB    [4][64][2048]
    unsigned short* yb     = xb;                                  // alias (x consumed by qkv GEMM)

    cvt_bf16<<<(BT * C_ / 4 + 255) / 256, 256, 0, stream>>>(x, xb, BT * C_ / 4);
    cvt_bf16<<<(C_ * L_ / 4 + 255) / 256, 256, 0, stream>>>(Wd, wdb, C_ * L_ / 4);
    wtrans<<<(L_ * C_ + 255) / 256, 256, 0, stream>>>(Wq, wqkvT, L_, C_, KSC);
    wtrans<<<(L_ * 128 + 255) / 256, 256, 0, stream>>>(Wkv, wqkvT + 1024 * 512, L_, 128, 1.0f);
    wtrans<<<(C_ * C_ + 255) / 256, 256, 0, stream>>>(Wp, wpT, C_, C_, 1.0f);

    // W_comb^T[1152][1024] = wqkvT[1152][512] @ (Wd[1024][512])^T   (72 blocks)
    gemm_bt<false><<<8 * 9, 256, 0, stream>>>(wqkvT, wdb, wcombT, QKV_N, C_, L_, 8);

    // qkv[8192][1152] = xb[8192][1024] @ W_comb (Bt = wcombT)        (576 blocks)
    gemm_bt<false><<<9 * 64, 256, 0, stream>>>(xb, wcombT, qkv, BT, QKV_N, C_, 9);

    vtrans<<<(B_ * 64 * T_ + 255) / 256, 256, 0, stream>>>(qkv, vt);

    flash<<<1024, 256, 0, stream>>>(qkv, vt, yb);

    // out[8192][1024] = y @ Wp                                        (512 blocks)
    gemm_bt<true><<<8 * 64, 256, 0, stream>>>(yb, wpT, out, BT, C_, C_, 8);
}

// Round 11
// 135.427 us; speedup vs baseline: 1.2775x; 1.0626x over previous
//
#include <hip/hip_runtime.h>
#include <hip/hip_bf16.h>

// ---------------------------------------------------------------------------
// MultiLatentAttention, R9:
//   5 dispatches total: prep (all converts fused) -> wcomb GEMM -> qkv GEMM
//   (with vtrans folded into epilogue) -> flash (R6 config) -> proj GEMM.
//   Weight-combine: qkv = x @ (Wd@[Wq*KSC | Wkv]).
// ---------------------------------------------------------------------------

typedef __attribute__((ext_vector_type(8))) short bf16x8;
typedef __attribute__((ext_vector_type(4))) float floatx4;
typedef __attribute__((ext_vector_type(4))) unsigned int uintx4;

#define B_   4
#define T_   2048
#define C_   1024
#define H_   16
#define D_   64
#define L_   512
#define QKV_N 1152   // 1024 q cols + 128 kv cols

__device__ __forceinline__ float EXP2F(float x) {
    float r;
    asm("v_exp_f32 %0, %1" : "=v"(r) : "v"(x));
    return r;
}

__device__ __forceinline__ unsigned short f2bf(float f) {
    unsigned int x = __float_as_uint(f);
    unsigned int r = (x + 0x7fffu + ((x >> 16) & 1u)) >> 16;
    return (unsigned short)r;
}

// pack two fp32 -> bf16x2 (lo in low half), single instruction
__device__ __forceinline__ unsigned int cvtpk_bf(float lo, float hi) {
    unsigned int r;
    asm("v_cvt_pk_bf16_f32 %0, %1, %2" : "=v"(r) : "v"(lo), "v"(hi));
    return r;
}

// D' = {D[0:31], S[0:31]}; S' = {D[32:63], S[32:63]}
__device__ __forceinline__ void pl32(unsigned int& d, unsigned int& s) {
    asm("v_permlane32_swap_b32 %0, %1" : "+v"(d), "+v"(s));
}
// 16-lane-group interleave swap
__device__ __forceinline__ void pl16(unsigned int& d, unsigned int& s) {
    asm("v_permlane16_swap_b32 %0, %1" : "+v"(d), "+v"(s));
}

// async global->LDS, 16B per lane. LDS dest = wave-uniform base + lane*16.
__device__ __forceinline__ void gload_lds16(const unsigned short* g, char* l) {
    __builtin_amdgcn_global_load_lds(
        (const __attribute__((address_space(1))) void*)g,
        (__attribute__((address_space(3))) void*)l,
        16, 0, 0);
}

// ---------------- fused preprocessing (1 kernel) ----------------
// blocks [0,8192):      x fp32 -> xb bf16 (4 elems/thread)
// blocks [8192,8704):   Wd fp32 -> wdb bf16 (4 elems/thread, no transpose)
// blocks [8704,10752):  Wq -> wqkvT[0:1024][512] transposed * KSC
// blocks [10752,11008): Wkv -> wqkvT[1024:1152][512] transposed
// blocks [11008,15104): Wp -> wpT[1024][1024] transposed
__global__ __launch_bounds__(256) void prep(const float* __restrict__ x, unsigned short* __restrict__ xb,
                                            const float* __restrict__ Wd, unsigned short* __restrict__ wdb,
                                            const float* __restrict__ Wq, const float* __restrict__ Wkv,
                                            unsigned short* __restrict__ wqkvT,
                                            const float* __restrict__ Wp, unsigned short* __restrict__ wpT,
                                            float ksc) {
    const int bid = blockIdx.x;
    const int tid = threadIdx.x;
    if (bid < 8192) {                       // x convert
        int i = bid * 256 + tid;
        float4 v = *(const float4*)(x + (size_t)i * 4);
        ushort4 o;
        o.x = f2bf(v.x); o.y = f2bf(v.y); o.z = f2bf(v.z); o.w = f2bf(v.w);
        *(ushort4*)(xb + (size_t)i * 4) = o;
    } else if (bid < 8704) {                // Wd convert (native layout = Bt operand)
        int i = (bid - 8192) * 256 + tid;
        float4 v = *(const float4*)(Wd + (size_t)i * 4);
        ushort4 o;
        o.x = f2bf(v.x); o.y = f2bf(v.y); o.z = f2bf(v.z); o.w = f2bf(v.w);
        *(ushort4*)(wdb + (size_t)i * 4) = o;
    } else if (bid < 10752) {               // Wq transpose*scale: [512][1024] -> [1024][512]
        int idx = (bid - 8704) * 256 + tid;     // over 1024*512
        int n = idx >> 9, k = idx & 511;
        wqkvT[idx] = f2bf(Wq[(size_t)k * 1024 + n] * ksc);
    } else if (bid < 11008) {               // Wkv transpose: [512][128] -> [128][512]
        int idx = (bid - 10752) * 256 + tid;    // over 128*512
        int n = idx >> 9, k = idx & 511;
        wqkvT[1024 * 512 + idx] = f2bf(Wkv[(size_t)k * 128 + n]);
    } else {                                // Wp transpose: [1024][1024] -> [1024][1024]
        int idx = (bid - 11008) * 256 + tid;    // over 1024*1024
        int n = idx >> 10, k = idx & 1023;
        wpT[idx] = f2bf(Wp[(size_t)k * 1024 + n]);
    }
}

// ---------------- generic bf16 GEMM: C[M][N] = A[M][K] * Bt[N][K]^T ----------------
// 1D grid (nwg % 8 == 0) with bijective XCD swizzle. Optional vtrans fold:
// epilogue elements with col >= 1088 also write Vt[b][col-1088][t].
#define BM 128
#define BN 128
#define BK 64

template <bool F32OUT, bool VTFOLD>
__global__ __launch_bounds__(256) void gemm_bt(const unsigned short* __restrict__ A,
                                               const unsigned short* __restrict__ Bt,
                                               void* __restrict__ Cout,
                                               unsigned short* __restrict__ Vtf,
                                               int M, int N, int K, int nbx) {
    __shared__ __align__(16) char ldsA[2][BM * BK * 2];
    __shared__ __align__(16) char ldsB[2][BN * BK * 2];
    const int tid = threadIdx.x;
    const int lane = tid & 63, wave = tid >> 6;
    const int lrow = lane & 15, lhi = lane >> 4;

    // XCD-aware bijective remap: xcd = bid%8 gets contiguous chunk of tiles
    const int bid = blockIdx.x;
    const int cpx = gridDim.x >> 3;           // nwg/8 (nwg % 8 == 0)
    const int swz = (bid & 7) * cpx + (bid >> 3);
    const int by = swz / nbx, bx = swz - by * nbx;
    const int bm = by * BM, bn = bx * BN;
    const int wm = (wave >> 1) * 64, wn = (wave & 1) * 64;

    // per-thread staging source pointers (source chunk pre-swizzled:
    // LDS slot cc holds global chunk cc^(row&7))
    const unsigned short* ap[4];
    const unsigned short* bp[4];
#pragma unroll
    for (int i = 0; i < 4; ++i) {
        int c = tid + i * 256;            // 1024 chunks of 16B per array
        int row = c >> 3;
        int sc = ((c & 7) ^ (row & 7)) * 8;
        ap[i] = A + (size_t)(bm + row) * K + sc;
        bp[i] = Bt + (size_t)(bn + row) * K + sc;
    }
    const int nk = K >> 6;
    floatx4 acc[4][4] = {};

    // prologue: stage k-step 0 into buf 0
#pragma unroll
    for (int i = 0; i < 4; ++i) {
        gload_lds16(ap[i], ldsA[0] + (i * 256 + wave * 64) * 16);
        gload_lds16(bp[i], ldsB[0] + (i * 256 + wave * 64) * 16);
        ap[i] += BK; bp[i] += BK;
    }

    for (int t = 0; t < nk; ++t) {
        const int cur = t & 1;
        if (t + 1 < nk) {
#pragma unroll
            for (int i = 0; i < 4; ++i) {
                gload_lds16(ap[i], ldsA[cur ^ 1] + (i * 256 + wave * 64) * 16);
                gload_lds16(bp[i], ldsB[cur ^ 1] + (i * 256 + wave * 64) * 16);
                ap[i] += BK; bp[i] += BK;
            }
            // counted: wait this tile's 8 loads; next tile's 8 stay in flight
            asm volatile("s_waitcnt vmcnt(8)" ::: "memory");
        } else {
            asm volatile("s_waitcnt vmcnt(0)" ::: "memory");
        }
        __builtin_amdgcn_s_barrier();
        __builtin_amdgcn_sched_barrier(0);

#pragma unroll
        for (int kk = 0; kk < 2; ++kk) {
            bf16x8 af[4], bfr[4];
#pragma unroll
            for (int m = 0; m < 4; ++m) {
                int row = wm + m * 16 + lrow;
                int colb = kk * 64 + lhi * 16;
                af[m] = *(const bf16x8*)(ldsA[cur] + row * 128 + (colb ^ ((row & 7) << 4)));
            }
#pragma unroll
            for (int n = 0; n < 4; ++n) {
                int row = wn + n * 16 + lrow;
                int colb = kk * 64 + lhi * 16;
                bfr[n] = *(const bf16x8*)(ldsB[cur] + row * 128 + (colb ^ ((row & 7) << 4)));
            }
#pragma unroll
            for (int m = 0; m < 4; ++m)
#pragma unroll
                for (int n = 0; n < 4; ++n)
                    acc[m][n] = __builtin_amdgcn_mfma_f32_16x16x32_bf16(af[m], bfr[n], acc[m][n], 0, 0, 0);
        }
        __builtin_amdgcn_sched_barrier(0);
        __builtin_amdgcn_s_barrier();   // all reads of buf[cur] done before restage
    }
#pragma unroll
    for (int m = 0; m < 4; ++m)
#pragma unroll
        for (int n = 0; n < 4; ++n)
#pragma unroll
            for (int r = 0; r < 4; ++r) {
                int row = bm + wm + m * 16 + lhi * 4 + r;
                int col = bn + wn + n * 16 + lrow;
                float v = acc[m][n][r];
                if (F32OUT)
                    ((float*)Cout)[(size_t)row * N + col] = v;
                else {
                    unsigned short bv = f2bf(v);
                    ((unsigned short*)Cout)[(size_t)row * N + col] = bv;
                    if (VTFOLD && col >= 1088) {
                        // vt[b][d][t]: b = row>>11, t = row&2047, d = col-1088
                        Vtf[(((size_t)(row >> 11) * 64 + (col - 1088)) << 11) | (row & 2047)] = bv;
                    }
                }
            }
}

// ---------------- flash attention (R6 config, proven 51.2us) ----------------
// 1024 blocks (16 q-tiles x 16 h x 4 b, heavy qt first), 256 threads;
// wave owns 32 q rows. Swapped QK^T (S^T = K@Q^T); q pre-scaled by
// 0.125*log2e so P = exp2(S); l via MFMA ones-column.
// P stays in registers (cvt_pk + permlane swaps). K/V triple-buffered,
// counted vmcnt(4), 1 barrier/step.
__global__ __launch_bounds__(256, 3) void flash(const unsigned short* __restrict__ QKV, // [B*T][1152]
                                                const unsigned short* __restrict__ Vt,  // [B][64][T]
                                                unsigned short* __restrict__ Y) {       // [B*T][C]
    const int id = blockIdx.x;
    const int qt = 15 - (id >> 6);      // heavy tiles dispatch first
    const int h = (id >> 2) & 15;
    const int b = id & 3;
    const int tid = threadIdx.x;
    const int lane = tid & 63, wave = tid >> 6;
    const int lrow = lane & 15, lhi = lane >> 4;

    __shared__ __align__(16) char ldsK[3][64 * 128];  // [s][d0..63] swizzled
    __shared__ __align__(16) char ldsV[3][64 * 128];  // [d][s0..63] swizzled

    const int qbase = qt * 128 + wave * 32;
    const unsigned short* KV = QKV + 1024;    // k rows, stride QKV_N
    const int nst = qt * 2 + 2;

    // per-thread staging source pointers (tile to stage next)
    const unsigned short* kp[2];
    const unsigned short* vp[2];
#pragma unroll
    for (int i = 0; i < 2; ++i) {
        int c = tid + i * 256;
        int row = c >> 3;
        int sc = ((c & 7) ^ (row & 7)) * 8;
        kp[i] = KV + ((size_t)(b * T_ + row)) * QKV_N + sc;
        vp[i] = Vt + ((size_t)(b * 64 + row)) * T_ + sc;
    }

    // Q fragments (B-operand): lane holds Q[qbase + nf*16 + lrow][kk*32 + lhi*8 + e]
    bf16x8 qf[2][2];
#pragma unroll
    for (int nf = 0; nf < 2; ++nf)
#pragma unroll
        for (int kk = 0; kk < 2; ++kk) {
            int trow = b * T_ + qbase + nf * 16 + lrow;
            int col = h * 64 + kk * 32 + lhi * 8;
            qf[nf][kk] = *(const bf16x8*)(QKV + (size_t)trow * QKV_N + col);
        }

    floatx4 o[2][4] = {};
    floatx4 ol[2] = {};   // row-sum accumulator (ones-column)

    const short one_bf = (short)0x3F80;
    const bf16x8 ones8 = {one_bf, one_bf, one_bf, one_bf, one_bf, one_bf, one_bf, one_bf};

    // prologue: stage tile 0 into buf 0
    char* kcur = ldsK[0];  char* kstg = ldsK[1];  char* kfre = ldsK[2];
    char* vcur = ldsV[0];  char* vstg = ldsV[1];  char* vfre = ldsV[2];
#pragma unroll
    for (int i = 0; i < 2; ++i) {
        gload_lds16(kp[i], kcur + (i * 256 + wave * 64) * 16);
        gload_lds16(vp[i], vcur + (i * 256 + wave * 64) * 16);
        kp[i] += 64 * QKV_N;
        vp[i] += 64;
    }

    for (int st = 0; st < nst; ++st) {
        // stage tile st+1 into stg (refetch last tile on final step to keep
        // the vmcnt count uniform)
        const bool more = (st + 1 < nst);
        const long kadj = more ? 0 : -(long)(64 * QKV_N);
        const long vadj = more ? 0 : -64L;
#pragma unroll
        for (int i = 0; i < 2; ++i) {
            gload_lds16(kp[i] + kadj, kstg + (i * 256 + wave * 64) * 16);
            gload_lds16(vp[i] + vadj, vstg + (i * 256 + wave * 64) * 16);
        }
        if (more) {
            kp[0] += 64 * QKV_N; kp[1] += 64 * QKV_N;
            vp[0] += 64;         vp[1] += 64;
        }
        // counted wait: this step's 4 loads (issued last iter) are the oldest
        asm volatile("s_waitcnt vmcnt(4)" ::: "memory");
        __builtin_amdgcn_s_barrier();
        __builtin_amdgcn_sched_barrier(0);

        if (st * 64 <= qbase + 31) {
            // S^T frags: row = s-local = mf*16+lhi*4+r, col = q-local = nf*16+lrow
            floatx4 s[4][2] = {};
#pragma unroll
            for (int kk = 0; kk < 2; ++kk) {
                bf16x8 kf[4];
#pragma unroll
                for (int mf = 0; mf < 4; ++mf) {
                    int row = mf * 16 + lrow;
                    int colb = kk * 64 + lhi * 16;
                    kf[mf] = *(const bf16x8*)(kcur + row * 128 + (colb ^ ((row & 7) << 4)));
                }
                __builtin_amdgcn_s_setprio(1);
#pragma unroll
                for (int mf = 0; mf < 4; ++mf)
#pragma unroll
                    for (int nf = 0; nf < 2; ++nf)
                        s[mf][nf] = __builtin_amdgcn_mfma_f32_16x16x32_bf16(kf[mf], qf[nf][kk], s[mf][nf], 0, 0, 0);
                __builtin_amdgcn_s_setprio(0);
            }

            // causal mask + P = exp2(S) (scale pre-folded into q)
#pragma unroll
            for (int nf = 0; nf < 2; ++nf) {
                if (st * 64 + 63 > qbase + nf * 16) {   // mask only near diagonal
                    int qg = qbase + nf * 16 + lrow;
#pragma unroll
                    for (int mf = 0; mf < 4; ++mf)
#pragma unroll
                        for (int r = 0; r < 4; ++r) {
                            int sg = st * 64 + mf * 16 + lhi * 4 + r;
                            if (sg > qg) s[mf][nf][r] = -1e30f;
                        }
                }
#pragma unroll
                for (int mf = 0; mf < 4; ++mf)
#pragma unroll
                    for (int rr = 0; rr < 4; ++rr)
                        s[mf][nf][rr] = EXP2F(s[mf][nf][rr]);
            }

            // in-register P^T -> PV A-fragment transform (cvt_pk + permlane)
            bf16x8 pfr[2][2];
#pragma unroll
            for (int nf = 0; nf < 2; ++nf)
#pragma unroll
                for (int ss = 0; ss < 2; ++ss) {
                    unsigned int A0 = cvtpk_bf(s[2 * ss][nf][0], s[2 * ss][nf][1]);
                    unsigned int A1 = cvtpk_bf(s[2 * ss][nf][2], s[2 * ss][nf][3]);
                    unsigned int B0 = cvtpk_bf(s[2 * ss + 1][nf][0], s[2 * ss + 1][nf][1]);
                    unsigned int B1 = cvtpk_bf(s[2 * ss + 1][nf][2], s[2 * ss + 1][nf][3]);
                    pl32(A0, B0); pl16(A0, B0);   // A0=word0, B0=word2
                    pl32(A1, B1); pl16(A1, B1);   // A1=word1, B1=word3
                    uintx4 pw; pw.x = A0; pw.y = A1; pw.z = B0; pw.w = B1;
                    pfr[nf][ss] = __builtin_bit_cast(bf16x8, pw);
                }

            // PV: O[q][d] += P[q][s] * V[s][d]; l[q] += P[q][s] * 1
#pragma unroll
            for (int ss = 0; ss < 2; ++ss) {
                bf16x8 vf[4];
#pragma unroll
                for (int dn = 0; dn < 4; ++dn) {
                    int row = dn * 16 + lrow;
                    int colb = ss * 64 + lhi * 16;
                    vf[dn] = *(const bf16x8*)(vcur + row * 128 + (colb ^ ((row & 7) << 4)));
                }
                __builtin_amdgcn_s_setprio(1);
#pragma unroll
                for (int m = 0; m < 2; ++m) {
#pragma unroll
                    for (int dn = 0; dn < 4; ++dn)
                        o[m][dn] = __builtin_amdgcn_mfma_f32_16x16x32_bf16(pfr[m][ss], vf[dn], o[m][dn], 0, 0, 0);
                    ol[m] = __builtin_amdgcn_mfma_f32_16x16x32_bf16(pfr[m][ss], ones8, ol[m], 0, 0, 0);
                }
                __builtin_amdgcn_s_setprio(0);
            }
        }

        // rotate buffers: cur <- stg <- fre <- cur
        char* t;
        t = kcur; kcur = kstg; kstg = kfre; kfre = t;
        t = vcur; vcur = vstg; vstg = vfre; vfre = t;
    }

    // epilogue: divide by l (ol[m][rr] is l for row m*16+lhi*4+rr), store y
#pragma unroll
    for (int m = 0; m < 2; ++m) {
        float linv[4];
#pragma unroll
        for (int rr = 0; rr < 4; ++rr) linv[rr] = __builtin_amdgcn_rcpf(ol[m][rr]);
#pragma unroll
        for (int dn = 0; dn < 4; ++dn)
#pragma unroll
            for (int rr = 0; rr < 4; ++rr) {
                int trow = b * T_ + qbase + m * 16 + lhi * 4 + rr;
                int col = h * 64 + dn * 16 + lrow;
                Y[(size_t)trow * C_ + col] = f2bf(o[m][dn][rr] * linv[rr]);
            }
    }
}

// ---------------------------------------------------------------------------
extern "C" void kernel_launch(void* const* d_in, const int* in_sizes, int n_in,
                              void* d_out, int out_size, void* d_ws, size_t ws_size,
                              hipStream_t stream) {
    (void)in_sizes; (void)n_in; (void)out_size; (void)ws_size;
    const float* x   = (const float*)d_in[0];
    const float* Wd  = (const float*)d_in[1];
    const float* Wq  = (const float*)d_in[2];
    const float* Wkv = (const float*)d_in[3];
    const float* Wp  = (const float*)d_in[4];
    float* out = (float*)d_out;
    char* ws = (char*)d_ws;

    const int BT = B_ * T_;  // 8192
    const float KSC = 0.125f * 1.44269504f;   // attn scale * log2(e), folded into Wq

    unsigned short* xb     = (unsigned short*)(ws + 0);           // 16 MB (reused as y)
    unsigned short* wqkvT  = (unsigned short*)(ws + 16777216);    // 1.125 MB [1152][512]
    unsigned short* wdb    = (unsigned short*)(ws + 17956864);    // 1 MB    [1024][512] (= Wd bf16, no transpose)
    unsigned short* wpT    = (unsigned short*)(ws + 19005440);    // 2 MB    [1024][1024]
    unsigned short* wcombT = (unsigned short*)(ws + 21102592);    // 2.25 MB [1152][1024]
    unsigned short* qkv    = (unsigned short*)(ws + 29491200);    // 18 MB   [8192][1152]
    unsigned short* vt     = (unsigned short*)(ws + 48365568);    // 1 MB    [4][64][2048]
    unsigned short* yb     = xb;                                  // alias (x consumed by qkv GEMM)

    // 1) all converts/transposes in one kernel
    prep<<<15104, 256, 0, stream>>>(x, xb, Wd, wdb, Wq, Wkv, wqkvT, Wp, wpT, KSC);

    // 2) W_comb^T[1152][1024] = wqkvT[1152][512] @ (Wd[1024][512])^T   (72 blocks)
    gemm_bt<false, false><<<8 * 9, 256, 0, stream>>>(wqkvT, wdb, wcombT, nullptr, QKV_N, C_, L_, 8);

    // 3) qkv[8192][1152] = xb @ W_comb; v cols also written transposed to vt (576 blocks)
    gemm_bt<false, true><<<9 * 64, 256, 0, stream>>>(xb, wcombT, qkv, vt, BT, QKV_N, C_, 9);

    // 4) flash attention
    flash<<<1024, 256, 0, stream>>>(qkv, vt, yb);

    // 5) out[8192][1024] = y @ Wp                                      (512 blocks)
    gemm_bt<true, false><<<8 * 64, 256, 0, stream>>>(yb, wpT, out, nullptr, BT, C_, C_, 8);
}